// Round 8
// baseline (29248.132 us; speedup 1.0000x reference)
//
#include <hip/hip_runtime.h>
#include <hip/hip_bf16.h>

typedef short s8v __attribute__((ext_vector_type(8)));
typedef float f4v __attribute__((ext_vector_type(4)));
typedef unsigned int u4v __attribute__((ext_vector_type(4)));
typedef unsigned int u2v __attribute__((ext_vector_type(2)));

#define NBLK 16
#define TPB 512

constexpr int BB = 32, TT = 512, DD = 512, HH = 1024;
constexpr int KK = DD + HH;          // 1536

// ---- workspace layout (bytes) ----
constexpr size_t OFF_WGT = 0;                                   // [2048][1536] bf16 (rows 0..1023 r-cols, 1024..2047 u-cols)
constexpr size_t SZ_WGT  = (size_t)2 * HH * KK * 2;
constexpr size_t OFF_WCT = OFF_WGT + SZ_WGT;                    // [1024][1536] bf16
constexpr size_t SZ_WCT  = (size_t)HH * KK * 2;
constexpr size_t OFF_XBF = OFF_WCT + SZ_WCT;                    // [32][512][512] bf16
constexpr size_t SZ_XBF  = (size_t)BB * TT * DD * 2;
constexpr size_t OFF_HPB = OFF_XBF + SZ_XBF;                    // h publish (coherent)
constexpr size_t SZ_PUB  = (size_t)BB * HH * 2;
constexpr size_t OFF_RPB = OFF_HPB + SZ_PUB;                    // rh publish (coherent)
constexpr size_t OFF_FLG = OFF_RPB + SZ_PUB;                    // 2 arrays x [16 blk][4 cs][2 rt] x 16 ints
constexpr int    FLAGN   = NBLK * 4 * 2 * 16;                   // 2048 ints per array
constexpr size_t SZ_FLG  = (size_t)2 * FLAGN * 4;               // 16,384

// ---------------------------------------------------------------------------
__global__ void wtr_kernel(const float* __restrict__ in, unsigned short* __restrict__ out, int N) {
    __shared__ float tl[32][33];
    int tx = threadIdx.x & 31, ty = threadIdx.x >> 5;
    int n0 = blockIdx.x * 32, k0 = blockIdx.y * 32;
#pragma unroll
    for (int r = ty; r < 32; r += 8) tl[r][tx] = in[(size_t)(k0 + r) * N + n0 + tx];
    __syncthreads();
#pragma unroll
    for (int r = ty; r < 32; r += 8) {
        __hip_bfloat16 h = __float2bfloat16(tl[tx][r]);
        out[(size_t)(n0 + r) * KK + k0 + tx] = *reinterpret_cast<unsigned short*>(&h);
    }
}

__global__ void xconv_kernel(const float* __restrict__ X, unsigned short* __restrict__ Xbf) {
    size_t i = ((size_t)blockIdx.x * 256 + threadIdx.x) * 4;
    float4 v = *reinterpret_cast<const float4*>(X + i);
    __hip_bfloat16 h0 = __float2bfloat16(v.x), h1 = __float2bfloat16(v.y);
    __hip_bfloat16 h2 = __float2bfloat16(v.z), h3 = __float2bfloat16(v.w);
    ushort4 o;
    o.x = *(unsigned short*)&h0; o.y = *(unsigned short*)&h1;
    o.z = *(unsigned short*)&h2; o.w = *(unsigned short*)&h3;
    *reinterpret_cast<ushort4*>(Xbf + i) = o;
}

// ---------------------------------------------------------------------------
// Proven coherent primitives (r2-r7): agent-scope atomics for flags, sc0 sc1
// loads/stores for exchanged data. No fences, no other cache-scope tricks.
__device__ __forceinline__ u4v cload16(const void* p) {
    u4v r; asm volatile("global_load_dwordx4 %0, %1, off sc0 sc1" : "=v"(r) : "v"(p) : "memory"); return r;
}
__device__ __forceinline__ void cstore8(void* p, u2v v) {
    asm volatile("global_store_dwordx2 %0, %1, off sc0 sc1" :: "v"(p), "v"(v) : "memory");
}
#define B16(x) __builtin_bit_cast(s8v, (x))

// Poll 64 producer-wave flags with 64 lanes (one flag each). Lanes spin
// independently; wave reconverges after the loop. No block barrier.
__device__ __forceinline__ void poll64(const int* f, int rt, int gen) {
    const int lane = threadIdx.x & 63;
    const int pb = lane >> 2, pcs = lane & 3;
    const int* fp = f + ((size_t)((pb * 4 + pcs) * 2 + rt)) * 16;
    while (__hip_atomic_load(fp, __ATOMIC_RELAXED, __HIP_MEMORY_SCOPE_AGENT) < gen)
        __builtin_amdgcn_s_sleep(1);
    asm volatile("" ::: "memory");     // keep subsequent coherent loads below the poll
}

#define MFMA(A, B, C) __builtin_amdgcn_mfma_f32_16x16x32_bf16((A), (B), (C), 0, 0, 0)

// ---------------------------------------------------------------------------
// Persistent kernel, 16 blocks x 512 threads (8 waves), fully wave-autonomous:
// block b owns r/u/cand columns [b*64, b*64+64); wave (cs,rt) owns the 16-col
// slice [b*64+cs*16, +16) x 16-row tile [rt*16, +16) over FULL K. Weights are
// streamed from L2 every step (9 MB total, ~1.2 MB per XCD — L2-resident).
// No __syncthreads in the main loop; no LDS weights; hprev/u in registers.
__global__ __launch_bounds__(TPB, 1) void gru_kernel(
    const unsigned short* __restrict__ Xbf,
    const unsigned short* __restrict__ WgT,
    const unsigned short* __restrict__ WcT,
    const float* __restrict__ bg,
    const float* __restrict__ bc,
    float* __restrict__ out,
    unsigned short* __restrict__ hpub,
    unsigned short* __restrict__ rpub,
    int* __restrict__ gflagA,
    int* __restrict__ gflagB)
{
    __shared__ unsigned short stg[8][16][16];   // per-wave transpose stage, 4 KB

    const int b    = blockIdx.x;
    const int tid  = threadIdx.x;
    const int wid  = tid >> 6;
    const int lane = tid & 63;
    const int l15  = lane & 15;
    const int lq   = lane >> 4;
    const int rt   = wid & 1;
    const int cs   = wid >> 1;                  // 0..3
    const int colw = b * 64 + cs * 16;          // wave's 16-col base
    const int arow = rt * 16 + l15;             // A-fragment batch row
    const int myflag = ((b * 4 + cs) * 2 + rt) * 16;

    // Weight row pointers (L2-streamed): row = output col, [KK] bf16 each.
    const s8v* wR = (const s8v*)(WgT + (size_t)(colw + l15) * KK);        // r col
    const s8v* wU = (const s8v*)(WgT + (size_t)(HH + colw + l15) * KK);   // u col
    const s8v* wC = (const s8v*)(WcT + (size_t)(colw + l15) * KK);        // cand col

    const float bgr = bg[colw + l15];
    const float bgu = bg[HH + colw + l15];
    const float bcv = bc[colw + l15];

    float hprev[4] = {0.f, 0.f, 0.f, 0.f};      // h[rt*16+lq*4+i][colw+l15]
    float ureg[4]  = {0.f, 0.f, 0.f, 0.f};

#pragma unroll 1
    for (int t = 0; t < TT; ++t) {
        const s8v* xp = (const s8v*)(Xbf + (size_t)arow * (TT * DD) + (size_t)t * DD);

        // ========== Phase A: gates (full K per wave). x-part first ==========
        f4v ar0 = {0,0,0,0}, ar1 = {0,0,0,0}, au0 = {0,0,0,0}, au1 = {0,0,0,0};
#pragma unroll
        for (int c = 0; c < 16; c += 2) {
            s8v x0 = xp[c * 4 + lq], x1 = xp[(c + 1) * 4 + lq];
            ar0 = MFMA(x0, wR[c * 4 + lq],       ar0);
            au0 = MFMA(x0, wU[c * 4 + lq],       au0);
            ar1 = MFMA(x1, wR[(c + 1) * 4 + lq], ar1);
            au1 = MFMA(x1, wU[(c + 1) * 4 + lq], au1);
        }

        if (t > 0) {
            poll64(gflagB, rt, t);               // h_{t-1}: all 64 producer waves
            const unsigned short* hp = hpub + (size_t)arow * HH + lq * 8;
            u4v ha[16], hb[8], hc[8];
#pragma unroll
            for (int j = 0; j < 16; ++j) ha[j] = cload16(hp + (size_t)j * 32);
#pragma unroll
            for (int j = 0; j < 8; ++j)  hb[j] = cload16(hp + (size_t)(16 + j) * 32);
#pragma unroll
            for (int j = 0; j < 16; j += 2) {    // consume ha (h chunks 0..15)
                ar0 = MFMA(B16(ha[j]),     wR[(16 + j) * 4 + lq], ar0);
                au0 = MFMA(B16(ha[j]),     wU[(16 + j) * 4 + lq], au0);
                ar1 = MFMA(B16(ha[j + 1]), wR[(17 + j) * 4 + lq], ar1);
                au1 = MFMA(B16(ha[j + 1]), wU[(17 + j) * 4 + lq], au1);
            }
#pragma unroll
            for (int j = 0; j < 8; ++j)  hc[j] = cload16(hp + (size_t)(24 + j) * 32);
#pragma unroll
            for (int j = 0; j < 8; j += 2) {     // consume hb (chunks 16..23)
                ar0 = MFMA(B16(hb[j]),     wR[(32 + j) * 4 + lq], ar0);
                au0 = MFMA(B16(hb[j]),     wU[(32 + j) * 4 + lq], au0);
                ar1 = MFMA(B16(hb[j + 1]), wR[(33 + j) * 4 + lq], ar1);
                au1 = MFMA(B16(hb[j + 1]), wU[(33 + j) * 4 + lq], au1);
            }
#pragma unroll
            for (int j = 0; j < 8; j += 2) {     // consume hc (chunks 24..31)
                ar0 = MFMA(B16(hc[j]),     wR[(40 + j) * 4 + lq], ar0);
                au0 = MFMA(B16(hc[j]),     wU[(40 + j) * 4 + lq], au0);
                ar1 = MFMA(B16(hc[j + 1]), wR[(41 + j) * 4 + lq], ar1);
                au1 = MFMA(B16(hc[j + 1]), wU[(41 + j) * 4 + lq], au1);
            }
        }

        // finalize gates (wave-local, no reduction needed)
        {
            f4v pr = ar0 + ar1, pu = au0 + au1;
#pragma unroll
            for (int i = 0; i < 4; ++i) {
                float r = 1.f / (1.f + __expf(-(pr[i] + bgr)));
                ureg[i] = 1.f / (1.f + __expf(-(pu[i] + bgu)));
                __hip_bfloat16 h16 = __float2bfloat16(r * hprev[i]);
                stg[wid][lq * 4 + i][l15] = *(unsigned short*)&h16;
            }
            if (t > 0) {                         // rh_0 == 0, never read
                int prow = lane >> 2, pc4 = (lane & 3) * 4;
                u2v v = *reinterpret_cast<const u2v*>(&stg[wid][prow][pc4]);  // same-wave LDS
                cstore8(rpub + (size_t)(rt * 16 + prow) * HH + colw + pc4, v);
                asm volatile("s_waitcnt vmcnt(0)" ::: "memory");
                if (lane == 0)
                    __hip_atomic_store(&gflagA[myflag], t,
                                       __ATOMIC_RELAXED, __HIP_MEMORY_SCOPE_AGENT);
            }
        }

        // ========== Phase B: candidate (full K per wave). x-part first ==========
        f4v c0 = {0,0,0,0}, c1 = {0,0,0,0};
#pragma unroll
        for (int c = 0; c < 16; c += 2) {
            c0 = MFMA(xp[c * 4 + lq],       wC[c * 4 + lq],       c0);
            c1 = MFMA(xp[(c + 1) * 4 + lq], wC[(c + 1) * 4 + lq], c1);
        }

        if (t > 0) {
            poll64(gflagA, rt, t);               // rh_t: all 64 producer waves
            const unsigned short* rp = rpub + (size_t)arow * HH + lq * 8;
            u4v ra[16], rb[8], rc[8];
#pragma unroll
            for (int j = 0; j < 16; ++j) ra[j] = cload16(rp + (size_t)j * 32);
#pragma unroll
            for (int j = 0; j < 8; ++j)  rb[j] = cload16(rp + (size_t)(16 + j) * 32);
#pragma unroll
            for (int j = 0; j < 16; j += 2) {
                c0 = MFMA(B16(ra[j]),     wC[(16 + j) * 4 + lq], c0);
                c1 = MFMA(B16(ra[j + 1]), wC[(17 + j) * 4 + lq], c1);
            }
#pragma unroll
            for (int j = 0; j < 8; ++j)  rc[j] = cload16(rp + (size_t)(24 + j) * 32);
#pragma unroll
            for (int j = 0; j < 8; j += 2) {
                c0 = MFMA(B16(rb[j]),     wC[(32 + j) * 4 + lq], c0);
                c1 = MFMA(B16(rb[j + 1]), wC[(33 + j) * 4 + lq], c1);
            }
#pragma unroll
            for (int j = 0; j < 8; j += 2) {
                c0 = MFMA(B16(rc[j]),     wC[(40 + j) * 4 + lq], c0);
                c1 = MFMA(B16(rc[j + 1]), wC[(41 + j) * 4 + lq], c1);
            }
        }

        // finalize h (wave-local), publish, flag, then out-stores
        {
            f4v pc = c0 + c1;
#pragma unroll
            for (int i = 0; i < 4; ++i) {
                float z = pc[i] + bcv;
                float e = __expf(2.f * z);
                float cv = 1.f - 2.f / (e + 1.f);
                float hn = ureg[i] * hprev[i] + (1.f - ureg[i]) * cv;
                hprev[i] = hn;
                __hip_bfloat16 h16 = __float2bfloat16(hn);
                stg[wid][lq * 4 + i][l15] = *(unsigned short*)&h16;
            }
            int prow = lane >> 2, pc4 = (lane & 3) * 4;
            u2v v = *reinterpret_cast<const u2v*>(&stg[wid][prow][pc4]);      // same-wave LDS
            cstore8(hpub + (size_t)(rt * 16 + prow) * HH + colw + pc4, v);
            asm volatile("s_waitcnt vmcnt(0)" ::: "memory");
            if (lane == 0)
                __hip_atomic_store(&gflagB[myflag], t + 1,
                                   __ATOMIC_RELAXED, __HIP_MEMORY_SCOPE_AGENT);
            // out stores AFTER the flag — off the rendezvous critical path
#pragma unroll
            for (int i = 0; i < 4; ++i) {
                int row = rt * 16 + lq * 4 + i;
                out[(size_t)row * (TT * HH) + (size_t)t * HH + colw + l15] = hprev[i];
            }
        }
    }
}

// ---------------------------------------------------------------------------
extern "C" void kernel_launch(void* const* d_in, const int* in_sizes, int n_in,
                              void* d_out, int out_size, void* d_ws, size_t ws_size,
                              hipStream_t stream) {
    const float* X  = (const float*)d_in[0];
    const float* gk = (const float*)d_in[1];
    const float* gb = (const float*)d_in[2];
    const float* ck = (const float*)d_in[3];
    const float* cb = (const float*)d_in[4];
    float* out = (float*)d_out;
    char* ws = (char*)d_ws;
    if (ws_size < OFF_FLG + SZ_FLG) return;

    unsigned short* WgT  = (unsigned short*)(ws + OFF_WGT);
    unsigned short* WcT  = (unsigned short*)(ws + OFF_WCT);
    unsigned short* Xbf  = (unsigned short*)(ws + OFF_XBF);
    unsigned short* hpub = (unsigned short*)(ws + OFF_HPB);
    unsigned short* rpub = (unsigned short*)(ws + OFF_RPB);
    int*            gflagA = (int*)(ws + OFF_FLG);
    int*            gflagB = gflagA + FLAGN;

    hipMemsetAsync(gflagA, 0, SZ_FLG, stream);

    dim3 tb(256);
    wtr_kernel<<<dim3(2 * HH / 32, KK / 32), tb, 0, stream>>>(gk, WgT, 2 * HH);
    wtr_kernel<<<dim3(HH / 32, KK / 32), tb, 0, stream>>>(ck, WcT, HH);
    xconv_kernel<<<(BB * TT * DD) / (256 * 4), tb, 0, stream>>>(X, Xbf);

    gru_kernel<<<NBLK, dim3(TPB), 0, stream>>>(Xbf, WgT, WcT, gb, cb, out,
                                               hpub, rpub, gflagA, gflagB);
}

// Round 9
// 4188.291 us; speedup vs baseline: 6.9833x; 6.9833x over previous
//
#include <hip/hip_runtime.h>
#include <hip/hip_bf16.h>

typedef short s8v __attribute__((ext_vector_type(8)));
typedef float f4v __attribute__((ext_vector_type(4)));
typedef unsigned int u4v __attribute__((ext_vector_type(4)));

#define NBLK 64
#define TPB 512

constexpr int BB = 32, TT = 512, DD = 512, HH = 1024;
constexpr int KK = DD + HH;          // 1536
constexpr int PK = KK + 8;           // padded LDS K-stride
constexpr int PK8 = PK / 8;
constexpr int K8 = KK / 8;

// ---- workspace layout (bytes) ----
constexpr size_t OFF_WGT = 0;
constexpr size_t SZ_WGT  = (size_t)2 * HH * KK * 2;
constexpr size_t OFF_WCT = OFF_WGT + SZ_WGT;
constexpr size_t SZ_WCT  = (size_t)HH * KK * 2;
constexpr size_t OFF_XBF = OFF_WCT + SZ_WCT;
constexpr size_t SZ_XBF  = (size_t)BB * TT * DD * 2;
constexpr size_t OFF_SUM = OFF_XBF + SZ_XBF;                    // sumw_g[2048] f32
constexpr size_t SZ_SUM  = (size_t)2 * HH * 4;
constexpr size_t OFF_HP8 = OFF_SUM + SZ_SUM;                    // h publish u8 [32][1024] (k'-layout)
constexpr size_t SZ_P8   = (size_t)BB * HH;
constexpr size_t OFF_RP8 = OFF_HP8 + SZ_P8;                     // r publish u8
constexpr size_t OFF_FLG = OFF_RP8 + SZ_P8;
constexpr size_t SZ_FLG  = (size_t)2 * NBLK * 2 * 16 * 4;       // 16,384

// ---------------------------------------------------------------------------
__global__ void wtr_kernel(const float* __restrict__ in, unsigned short* __restrict__ out, int N) {
    __shared__ float tl[32][33];
    int tx = threadIdx.x & 31, ty = threadIdx.x >> 5;
    int n0 = blockIdx.x * 32, k0 = blockIdx.y * 32;
#pragma unroll
    for (int r = ty; r < 32; r += 8) tl[r][tx] = in[(size_t)(k0 + r) * N + n0 + tx];
    __syncthreads();
#pragma unroll
    for (int r = ty; r < 32; r += 8) {
        __hip_bfloat16 h = __float2bfloat16(tl[tx][r]);
        out[(size_t)(n0 + r) * KK + k0 + tx] = *reinterpret_cast<unsigned short*>(&h);
    }
}

__global__ void xconv_kernel(const float* __restrict__ X, unsigned short* __restrict__ Xbf) {
    size_t i = ((size_t)blockIdx.x * 256 + threadIdx.x) * 4;
    float4 v = *reinterpret_cast<const float4*>(X + i);
    __hip_bfloat16 h0 = __float2bfloat16(v.x), h1 = __float2bfloat16(v.y);
    __hip_bfloat16 h2 = __float2bfloat16(v.z), h3 = __float2bfloat16(v.w);
    ushort4 o;
    o.x = *(unsigned short*)&h0; o.y = *(unsigned short*)&h1;
    o.z = *(unsigned short*)&h2; o.w = *(unsigned short*)&h3;
    *reinterpret_cast<ushort4*>(Xbf + i) = o;
}

// Column sums of the gate kernel's h-part rows (k in [512,1536)) — needed for
// the u8 fixed-point affine correction  z = x_acc + h_acc/127 - (128/127)*sumw.
__global__ void sumw_kernel(const float* __restrict__ gk, float* __restrict__ sums) {
    int col = blockIdx.x * 256 + threadIdx.x;      // 0..2047
    float s = 0.f;
    for (int k = DD; k < KK; ++k) s += gk[(size_t)k * (2 * HH) + col];
    sums[col] = s;
}

// ---------------------------------------------------------------------------
// Proven coherent primitives (r2-r7): agent-scope atomics for flags, sc0 sc1
// (SYSTEM scope) loads/stores for exchanged data. Lone sc0/sc1 is SE/device
// scope — NOT coherent across CUs (r5 deadlock). Never use anything else.
__device__ __forceinline__ u4v cload16(const void* p) {
    u4v r; asm volatile("global_load_dwordx4 %0, %1, off sc0 sc1" : "=v"(r) : "v"(p) : "memory"); return r;
}
__device__ __forceinline__ void cstore8(void* p, unsigned long long v) {
    asm volatile("global_store_dwordx2 %0, %1, off sc0 sc1" :: "v"(p), "v"(v) : "memory");
}
#define B16(x) __builtin_bit_cast(s8v, (x))
#define WAIT_VM(n) do { asm volatile("s_waitcnt vmcnt(" #n ")" ::: "memory"); \
                        __builtin_amdgcn_sched_barrier(0); } while (0)

// Per-wave poll: lanes 0..15 poll the 16 producer-wave flags this wave's
// K-slice depends on. No block barrier.
__device__ __forceinline__ void poll16(const int* f, int blk0, int rtw, int gen, int lane) {
    if (lane < 16) {
        const int* fp = f + ((size_t)(blk0 + lane) * 2 + rtw) * 16;
        while (__hip_atomic_load(fp, __ATOMIC_RELAXED, __HIP_MEMORY_SCOPE_AGENT) < gen)
            __builtin_amdgcn_s_sleep(1);
    }
    asm volatile("" ::: "memory");
}

#define MFMA(A, B, C) __builtin_amdgcn_mfma_f32_16x16x32_bf16((A), (B), (C), 0, 0, 0)

// u8 -> exact bf16 pair (ints <=255 are exact in bf16; low16 of f32 bits are 0)
__device__ __forceinline__ unsigned int pkint(unsigned int w) {
    float f0 = (float)(w & 0xffu);
    float f1 = (float)((w >> 8) & 0xffu);
    return __builtin_bit_cast(unsigned int, f1) | (__builtin_bit_cast(unsigned int, f0) >> 16);
}
__device__ __forceinline__ s8v hfrag(unsigned int d0, unsigned int d1) {
    u4v u; u[0] = pkint(d0); u[1] = pkint(d0 >> 16); u[2] = pkint(d1); u[3] = pkint(d1 >> 16);
    return __builtin_bit_cast(s8v, u);
}
// rh = ((qh-128)/127) * (qr/255), packed to bf16 (truncation)
__device__ __forceinline__ unsigned int pkrh(unsigned int hw, unsigned int rw) {
    const float A  = 1.f / (127.f * 255.f);
    const float Bc = -128.f / (127.f * 255.f);
    float h0 = fmaf((float)(hw & 0xffu), A, Bc);
    float h1 = fmaf((float)((hw >> 8) & 0xffu), A, Bc);
    float p0 = h0 * (float)(rw & 0xffu);
    float p1 = h1 * (float)((rw >> 8) & 0xffu);
    return (__builtin_bit_cast(unsigned int, p1) & 0xffff0000u) |
           (__builtin_bit_cast(unsigned int, p0) >> 16);
}
__device__ __forceinline__ s8v rhfrag(unsigned int hd0, unsigned int hd1,
                                      unsigned int rd0, unsigned int rd1) {
    u4v u; u[0] = pkrh(hd0, rd0); u[1] = pkrh(hd0 >> 16, rd0 >> 16);
    u[2] = pkrh(hd1, rd1); u[3] = pkrh(hd1 >> 16, rd1 >> 16);
    return __builtin_bit_cast(s8v, u);
}

// ---------------------------------------------------------------------------
// Persistent kernel, 64 blocks x 512 threads (8 waves), 1 block/CU.
// Block b owns r/u/cand columns [b*16, b*16+16).
// Waves: ks = wid>>1 (4-way K-split), rt = wid&1 (16-row batch tile).
// u8 publish layout (k'-space): k = C*32 + L*8 + j  ->  k' = L*256 + C*8 + j.
// Consumer lane (lq,ks): contiguous 64 B at lq*256 + ks*64 (4x16B loads).
// Producer block b: per row, two 8B runs at ((b&1)*2+run)*256 + (b>>1)*8.
__global__ __launch_bounds__(TPB, 1) void gru_kernel(
    const unsigned short* __restrict__ Xbf,
    const unsigned short* __restrict__ WgT,
    const unsigned short* __restrict__ WcT,
    const float* __restrict__ bg,
    const float* __restrict__ bc,
    const float* __restrict__ sumw,
    float* __restrict__ out,
    unsigned char* __restrict__ hp8,
    unsigned char* __restrict__ rp8,
    int* __restrict__ gflagA,
    int* __restrict__ gflagB)
{
    __shared__ unsigned short sWg[32 * PK];        // 98,816 B
    __shared__ unsigned short sWc[16 * PK];        // 49,408 B
    __shared__ float sP[3][2][2][16][16];          // 12,288 B
    __shared__ unsigned long long stgq[2][16][2];  //    512 B  (u8 16x16 stage/rt)

    const int b    = blockIdx.x;
    const int tid  = threadIdx.x;
    const int wid  = tid >> 6;
    const int lane = tid & 63;
    const int l15  = lane & 15;
    const int lq   = lane >> 4;
    const int ks   = wid >> 1;
    const int rt   = wid & 1;
    const int roff = rt * 16;
    const int arow = roff + l15;
    const int bcol0= b * 16;

    // ---- stage weight slices into LDS (once) ----
    {
        s8v* dst = (s8v*)sWg;
        for (int idx = tid; idx < 32 * K8; idx += TPB) {
            int c = idx / K8, k8 = idx % K8;
            int gc = (c < 16) ? (bcol0 + c) : (HH + bcol0 + (c - 16));
            dst[c * PK8 + k8] = ((const s8v*)(WgT + (size_t)gc * KK))[k8];
        }
        s8v* dst2 = (s8v*)sWc;
        for (int idx = tid; idx < 16 * K8; idx += TPB) {
            int c = idx / K8, k8 = idx % K8;
            dst2[c * PK8 + k8] = ((const s8v*)(WcT + (size_t)(bcol0 + c) * KK))[k8];
        }
    }

    const float bgr  = bg[bcol0 + l15];
    const float bgu  = bg[HH + bcol0 + l15];
    const float bcv  = bc[bcol0 + l15];
    const float corR = (128.f / 127.f) * sumw[bcol0 + l15];
    const float corU = (128.f / 127.f) * sumw[HH + bcol0 + l15];
    const int   ccol = bcol0 + l15;

    const s8v* sWg8 = (const s8v*)sWg;
    const s8v* sWc8 = (const s8v*)sWc;
    const s8v* bwr = sWg8 + l15 * PK8 + lq;          // r-col weights
    const s8v* bwu = sWg8 + (16 + l15) * PK8 + lq;   // u-col weights
    const s8v* bwc = sWc8 + l15 * PK8 + lq;          // cand weights
    const s8v* bwrx = bwr + 16 * ks;                 // x chunks [4ks..4ks+4)
    const s8v* bwux = bwu + 16 * ks;
    const s8v* bwrh = bwr + 64 + 32 * ks;            // h chunks [8ks..8ks+8)
    const s8v* bwuh = bwu + 64 + 32 * ks;
    const s8v* bwcx = bwc + 16 * ks;
    const s8v* bwch = bwc + 64 + 32 * ks;

    float hprev[4] = {0.f, 0.f, 0.f, 0.f};   // valid in ks==0 waves
    float ureg[4]  = {0.f, 0.f, 0.f, 0.f};

    __syncthreads();

#pragma unroll 1
    for (int t = 0; t < TT; ++t) {
        const s8v* xk = (const s8v*)(Xbf + (size_t)arow * (TT * DD) + (size_t)t * DD) + lq + 16 * ks;
        s8v x0 = xk[0], x1 = xk[4], x2 = xk[8], x3 = xk[12];   // shared by A & B

        // ========== Phase A: gates. poll -> issue loads -> x-MFMAs in shadow ==========
        f4v axr = {0,0,0,0}, axu = {0,0,0,0}, ahr = {0,0,0,0}, ahu = {0,0,0,0};
        u4v hq0, hq1, hq2, hq3;
        if (t > 0) {
            poll16(gflagB, ks * 16, rt, t, lane);    // h_{t-1} from my 16 producers
            const unsigned char* hp = hp8 + (size_t)arow * HH + lq * 256 + ks * 64;
            hq0 = cload16(hp); hq1 = cload16(hp + 16);
            hq2 = cload16(hp + 32); hq3 = cload16(hp + 48);
            axr = MFMA(x0, bwrx[0],  axr); axu = MFMA(x0, bwux[0],  axu);
            axr = MFMA(x1, bwrx[4],  axr); axu = MFMA(x1, bwux[4],  axu);
            axr = MFMA(x2, bwrx[8],  axr); axu = MFMA(x2, bwux[8],  axu);
            axr = MFMA(x3, bwrx[12], axr); axu = MFMA(x3, bwux[12], axu);
            WAIT_VM(2);
            { s8v f;
              f = hfrag(hq0[0], hq0[1]); ahr = MFMA(f, bwrh[0],  ahr); ahu = MFMA(f, bwuh[0],  ahu);
              f = hfrag(hq0[2], hq0[3]); ahr = MFMA(f, bwrh[4],  ahr); ahu = MFMA(f, bwuh[4],  ahu);
              f = hfrag(hq1[0], hq1[1]); ahr = MFMA(f, bwrh[8],  ahr); ahu = MFMA(f, bwuh[8],  ahu);
              f = hfrag(hq1[2], hq1[3]); ahr = MFMA(f, bwrh[12], ahr); ahu = MFMA(f, bwuh[12], ahu); }
            WAIT_VM(0);
            { s8v f;
              f = hfrag(hq2[0], hq2[1]); ahr = MFMA(f, bwrh[16], ahr); ahu = MFMA(f, bwuh[16], ahu);
              f = hfrag(hq2[2], hq2[3]); ahr = MFMA(f, bwrh[20], ahr); ahu = MFMA(f, bwuh[20], ahu);
              f = hfrag(hq3[0], hq3[1]); ahr = MFMA(f, bwrh[24], ahr); ahu = MFMA(f, bwuh[24], ahu);
              f = hfrag(hq3[2], hq3[3]); ahr = MFMA(f, bwrh[28], ahr); ahu = MFMA(f, bwuh[28], ahu); }
        } else {
            axr = MFMA(x0, bwrx[0],  axr); axu = MFMA(x0, bwux[0],  axu);
            axr = MFMA(x1, bwrx[4],  axr); axu = MFMA(x1, bwux[4],  axu);
            axr = MFMA(x2, bwrx[8],  axr); axu = MFMA(x2, bwux[8],  axu);
            axr = MFMA(x3, bwrx[12], axr); axu = MFMA(x3, bwux[12], axu);
        }
        f4v pr = axr + ahr * (1.f / 127.f);
        f4v pu = axu + ahu * (1.f / 127.f);

        if (ks > 0) {
#pragma unroll
            for (int i = 0; i < 4; ++i) {
                sP[ks - 1][rt][0][lq * 4 + i][l15] = pr[i];
                sP[ks - 1][rt][1][lq * 4 + i][l15] = pu[i];
            }
        }
        __syncthreads();                             // S1: A partials ready
        float zr[4], zu[4];
        if (ks == 0) {
            float br = (t > 0) ? (bgr - corR) : bgr;
            float bu = (t > 0) ? (bgu - corU) : bgu;
#pragma unroll
            for (int i = 0; i < 4; ++i) {
                int rr = lq * 4 + i;
                zr[i] = pr[i] + sP[0][rt][0][rr][l15] + sP[1][rt][0][rr][l15]
                              + sP[2][rt][0][rr][l15] + br;
                zu[i] = pu[i] + sP[0][rt][1][rr][l15] + sP[1][rt][1][rr][l15]
                              + sP[2][rt][1][rr][l15] + bu;
            }
        }
        __syncthreads();                             // S2: sP free for phase B
        if (ks == 0) {
#pragma unroll
            for (int i = 0; i < 4; ++i) {
                float r = 1.f / (1.f + __expf(-zr[i]));
                ureg[i] = 1.f / (1.f + __expf(-zu[i]));
                float qr = __builtin_rintf(r * 255.f);
                ((unsigned char*)&stgq[rt][lq * 4 + i][0])[l15] = (unsigned char)qr;
            }
            if (t > 0) {                             // rh_0 == 0, r_0 never needed
                if (lane < 32) {
                    int prow = lane >> 1, run = lane & 1;
                    unsigned long long v = stgq[rt][prow][run];
                    cstore8(rp8 + (size_t)(roff + prow) * HH + ((b & 1) * 2 + run) * 256 + (b >> 1) * 8, v);
                }
                asm volatile("s_waitcnt vmcnt(0)" ::: "memory");
                if (lane == 0)
                    __hip_atomic_store(&gflagA[(b * 2 + rt) * 16], t,
                                       __ATOMIC_RELAXED, __HIP_MEMORY_SCOPE_AGENT);
            }
        }

        // ========== Phase B: candidate. poll -> loads -> x-MFMAs in shadow ==========
        f4v cx = {0,0,0,0}, ch = {0,0,0,0};
        if (t > 0) {
            poll16(gflagA, ks * 16, rt, t, lane);    // r_t from my 16 producers
            const unsigned char* rp = rp8 + (size_t)arow * HH + lq * 256 + ks * 64;
            u4v rq0 = cload16(rp),      rq1 = cload16(rp + 16);
            u4v rq2 = cload16(rp + 32), rq3 = cload16(rp + 48);
            cx = MFMA(x0, bwcx[0],  cx); cx = MFMA(x1, bwcx[4],  cx);
            cx = MFMA(x2, bwcx[8],  cx); cx = MFMA(x3, bwcx[12], cx);
            WAIT_VM(2);
            { s8v f;
              f = rhfrag(hq0[0], hq0[1], rq0[0], rq0[1]); ch = MFMA(f, bwch[0],  ch);
              f = rhfrag(hq0[2], hq0[3], rq0[2], rq0[3]); ch = MFMA(f, bwch[4],  ch);
              f = rhfrag(hq1[0], hq1[1], rq1[0], rq1[1]); ch = MFMA(f, bwch[8],  ch);
              f = rhfrag(hq1[2], hq1[3], rq1[2], rq1[3]); ch = MFMA(f, bwch[12], ch); }
            WAIT_VM(0);
            { s8v f;
              f = rhfrag(hq2[0], hq2[1], rq2[0], rq2[1]); ch = MFMA(f, bwch[16], ch);
              f = rhfrag(hq2[2], hq2[3], rq2[2], rq2[3]); ch = MFMA(f, bwch[20], ch);
              f = rhfrag(hq3[0], hq3[1], rq3[0], rq3[1]); ch = MFMA(f, bwch[24], ch);
              f = rhfrag(hq3[2], hq3[3], rq3[2], rq3[3]); ch = MFMA(f, bwch[28], ch); }
        } else {
            cx = MFMA(x0, bwcx[0],  cx); cx = MFMA(x1, bwcx[4],  cx);
            cx = MFMA(x2, bwcx[8],  cx); cx = MFMA(x3, bwcx[12], cx);
        }
        f4v pc = cx + ch;

        if (ks > 0) {
#pragma unroll
            for (int i = 0; i < 4; ++i) sP[ks - 1][rt][0][lq * 4 + i][l15] = pc[i];
        }
        __syncthreads();                             // S3: B partials ready
        float zc[4];
        if (ks == 0) {
#pragma unroll
            for (int i = 0; i < 4; ++i) {
                int rr = lq * 4 + i;
                zc[i] = pc[i] + sP[0][rt][0][rr][l15] + sP[1][rt][0][rr][l15]
                              + sP[2][rt][0][rr][l15] + bcv;
            }
        }
        __syncthreads();                             // S4: sP free for next step
        if (ks == 0) {
#pragma unroll
            for (int i = 0; i < 4; ++i) {
                float e = __expf(2.f * zc[i]);
                float cv = 1.f - 2.f / (e + 1.f);
                float hn = ureg[i] * hprev[i] + (1.f - ureg[i]) * cv;
                hprev[i] = hn;
                float qh = __builtin_rintf(hn * 127.f) + 128.f;
                ((unsigned char*)&stgq[rt][lq * 4 + i][0])[l15] = (unsigned char)qh;
            }
            if (lane < 32) {
                int prow = lane >> 1, run = lane & 1;
                unsigned long long v = stgq[rt][prow][run];
                cstore8(hp8 + (size_t)(roff + prow) * HH + ((b & 1) * 2 + run) * 256 + (b >> 1) * 8, v);
            }
            asm volatile("s_waitcnt vmcnt(0)" ::: "memory");
            if (lane == 0)
                __hip_atomic_store(&gflagB[(b * 2 + rt) * 16], t + 1,
                                   __ATOMIC_RELAXED, __HIP_MEMORY_SCOPE_AGENT);
            // out stores AFTER the flag — off the rendezvous critical path
#pragma unroll
            for (int i = 0; i < 4; ++i) {
                int row = roff + lq * 4 + i;
                out[(size_t)row * (TT * HH) + (size_t)t * HH + ccol] = hprev[i];
            }
        }
    }
}

// ---------------------------------------------------------------------------
extern "C" void kernel_launch(void* const* d_in, const int* in_sizes, int n_in,
                              void* d_out, int out_size, void* d_ws, size_t ws_size,
                              hipStream_t stream) {
    const float* X  = (const float*)d_in[0];
    const float* gk = (const float*)d_in[1];
    const float* gb = (const float*)d_in[2];
    const float* ck = (const float*)d_in[3];
    const float* cb = (const float*)d_in[4];
    float* out = (float*)d_out;
    char* ws = (char*)d_ws;
    if (ws_size < OFF_FLG + SZ_FLG) return;

    unsigned short* WgT  = (unsigned short*)(ws + OFF_WGT);
    unsigned short* WcT  = (unsigned short*)(ws + OFF_WCT);
    unsigned short* Xbf  = (unsigned short*)(ws + OFF_XBF);
    float*          sums = (float*)(ws + OFF_SUM);
    unsigned char*  hp8  = (unsigned char*)(ws + OFF_HP8);
    unsigned char*  rp8  = (unsigned char*)(ws + OFF_RP8);
    int*            gflagA = (int*)(ws + OFF_FLG);
    int*            gflagB = gflagA + NBLK * 2 * 16;

    hipMemsetAsync(gflagA, 0, SZ_FLG, stream);

    dim3 tb(256);
    wtr_kernel<<<dim3(2 * HH / 32, KK / 32), tb, 0, stream>>>(gk, WgT, 2 * HH);
    wtr_kernel<<<dim3(HH / 32, KK / 32), tb, 0, stream>>>(ck, WcT, HH);
    xconv_kernel<<<(BB * TT * DD) / (256 * 4), tb, 0, stream>>>(X, Xbf);
    sumw_kernel<<<dim3(2 * HH / 256), tb, 0, stream>>>(gk, sums);

    gru_kernel<<<NBLK, dim3(TPB), 0, stream>>>(Xbf, WgT, WcT, gb, cb, sums, out,
                                               hp8, rp8, gflagA, gflagB);
}

// Round 10
// 4024.805 us; speedup vs baseline: 7.2670x; 1.0406x over previous
//
#include <hip/hip_runtime.h>
#include <hip/hip_bf16.h>

typedef short s8v __attribute__((ext_vector_type(8)));
typedef float f4v __attribute__((ext_vector_type(4)));
typedef unsigned int u4v __attribute__((ext_vector_type(4)));
typedef unsigned int u2v __attribute__((ext_vector_type(2)));

#define NBLK 64
#define TPB 512

constexpr int BB = 32, TT = 512, DD = 512, HH = 1024;
constexpr int KK = DD + HH;          // 1536
constexpr int PK = KK + 8;           // padded LDS K-stride
constexpr int PK8 = PK / 8;
constexpr int K8 = KK / 8;
constexpr size_t BBHH = (size_t)BB * HH;   // elements per publish slot

// ---- workspace layout (bytes) ----
constexpr size_t OFF_WGT = 0;
constexpr size_t SZ_WGT  = (size_t)2 * HH * KK * 2;
constexpr size_t OFF_WCT = OFF_WGT + SZ_WGT;
constexpr size_t SZ_WCT  = (size_t)HH * KK * 2;
constexpr size_t OFF_XBF = OFF_WCT + SZ_WCT;
constexpr size_t SZ_XBF  = (size_t)BB * TT * DD * 2;
constexpr size_t OFF_HPB = OFF_XBF + SZ_XBF;
constexpr size_t SZ_PUB1 = BBHH * 2;                       // 65,536 (one slot)
constexpr size_t SZ_PUBT = SZ_PUB1 * TT;                   // 33,554,432 (T-deep)
constexpr size_t SZ_FLG  = (size_t)2 * NBLK * 2 * 16 * 4;  // 16,384
// deep layout (generation-indexed publish):
constexpr size_t OFF_RPB_D = OFF_HPB + SZ_PUBT;
constexpr size_t OFF_FLG_D = OFF_RPB_D + SZ_PUBT;
constexpr size_t NEED_D    = OFF_FLG_D + SZ_FLG;           // ~93.3 MB
// shallow layout (r7-exact fallback):
constexpr size_t OFF_RPB_S = OFF_HPB + SZ_PUB1;
constexpr size_t OFF_FLG_S = OFF_RPB_S + SZ_PUB1;
constexpr size_t NEED_S    = OFF_FLG_S + SZ_FLG;

// ---------------------------------------------------------------------------
__global__ void wtr_kernel(const float* __restrict__ in, unsigned short* __restrict__ out, int N) {
    __shared__ float tl[32][33];
    int tx = threadIdx.x & 31, ty = threadIdx.x >> 5;
    int n0 = blockIdx.x * 32, k0 = blockIdx.y * 32;
#pragma unroll
    for (int r = ty; r < 32; r += 8) tl[r][tx] = in[(size_t)(k0 + r) * N + n0 + tx];
    __syncthreads();
#pragma unroll
    for (int r = ty; r < 32; r += 8) {
        __hip_bfloat16 h = __float2bfloat16(tl[tx][r]);
        out[(size_t)(n0 + r) * KK + k0 + tx] = *reinterpret_cast<unsigned short*>(&h);
    }
}

__global__ void xconv_kernel(const float* __restrict__ X, unsigned short* __restrict__ Xbf) {
    size_t i = ((size_t)blockIdx.x * 256 + threadIdx.x) * 4;
    float4 v = *reinterpret_cast<const float4*>(X + i);
    __hip_bfloat16 h0 = __float2bfloat16(v.x), h1 = __float2bfloat16(v.y);
    __hip_bfloat16 h2 = __float2bfloat16(v.z), h3 = __float2bfloat16(v.w);
    ushort4 o;
    o.x = *(unsigned short*)&h0; o.y = *(unsigned short*)&h1;
    o.z = *(unsigned short*)&h2; o.w = *(unsigned short*)&h3;
    *reinterpret_cast<ushort4*>(Xbf + i) = o;
}

// ---------------------------------------------------------------------------
// Proven coherent primitives: agent-scope atomics for flags; sc0 sc1 stores
// for exchanged data (write-through to the coherence point). Consumer side:
//   shallow mode: sc0 sc1 loads (r7-proven).
//   deep mode:    PLAIN cached loads — safe because every publish address is
//                 written exactly once per dispatch (generation-indexed slots),
//                 all reads are flag-ordered after the write, and dispatch-
//                 boundary acquire fences invalidate L1/L2 between replays.
__device__ __forceinline__ u4v cload16(const void* p) {
    u4v r; asm volatile("global_load_dwordx4 %0, %1, off sc0 sc1" : "=v"(r) : "v"(p) : "memory"); return r;
}
__device__ __forceinline__ void cstore8(void* p, u2v v) {
    asm volatile("global_store_dwordx2 %0, %1, off sc0 sc1" :: "v"(p), "v"(v) : "memory");
}
#define B16(x) __builtin_bit_cast(s8v, (x))
#define WAIT_VM(n) do { asm volatile("s_waitcnt vmcnt(" #n ")" ::: "memory"); \
                        __builtin_amdgcn_sched_barrier(0); } while (0)

// Per-wave poll: lanes 0..15 poll the 16 producer-wave flags this wave's
// K-slice depends on. No block barrier.
__device__ __forceinline__ void poll16(const int* f, int blk0, int rtw, int gen, int lane) {
    if (lane < 16) {
        const int* fp = f + ((size_t)(blk0 + lane) * 2 + rtw) * 16;
        while (__hip_atomic_load(fp, __ATOMIC_RELAXED, __HIP_MEMORY_SCOPE_AGENT) < gen)
            __builtin_amdgcn_s_sleep(1);
    }
    asm volatile("" ::: "memory");     // keep subsequent loads below the poll
}

#define MFMA(A, B, C) __builtin_amdgcn_mfma_f32_16x16x32_bf16((A), (B), (C), 0, 0, 0)

// ---------------------------------------------------------------------------
// Persistent kernel, 64 blocks x 512 threads (8 waves), 1 block/CU.
// Block b owns r/u/cand columns [b*16, b*16+16).
// Waves: ks = wid>>1 (4-way K-split), rt = wid&1 (16-row batch tile).
// DEEP: publish slots indexed by t (write-once addresses, cached reads).
template<bool DEEP>
__global__ __launch_bounds__(TPB, 1) void gru_kernel(
    const unsigned short* __restrict__ Xbf,
    const unsigned short* __restrict__ WgT,
    const unsigned short* __restrict__ WcT,
    const float* __restrict__ bg,
    const float* __restrict__ bc,
    float* __restrict__ out,
    unsigned short* __restrict__ hpub,
    unsigned short* __restrict__ rpub,
    int* __restrict__ gflagA,
    int* __restrict__ gflagB)
{
    __shared__ unsigned short sWg[32 * PK];        // 98,816 B
    __shared__ unsigned short sWc[16 * PK];        // 49,408 B
    __shared__ float sP[3][2][2][16][16];          // 12,288 B
    __shared__ unsigned short sStage[2][16][16];   //  1,024 B (per-rt transpose stage)

    const int b    = blockIdx.x;
    const int tid  = threadIdx.x;
    const int wid  = tid >> 6;
    const int lane = tid & 63;
    const int l15  = lane & 15;
    const int lq   = lane >> 4;
    const int ks   = wid >> 1;
    const int rt   = wid & 1;
    const int roff = rt * 16;
    const int arow = roff + l15;
    const int bcol0= b * 16;

    // ---- stage weight slices into LDS (once) ----
    {
        s8v* dst = (s8v*)sWg;
        for (int idx = tid; idx < 32 * K8; idx += TPB) {
            int c = idx / K8, k8 = idx % K8;
            int gc = (c < 16) ? (bcol0 + c) : (HH + bcol0 + (c - 16));
            dst[c * PK8 + k8] = ((const s8v*)(WgT + (size_t)gc * KK))[k8];
        }
        s8v* dst2 = (s8v*)sWc;
        for (int idx = tid; idx < 16 * K8; idx += TPB) {
            int c = idx / K8, k8 = idx % K8;
            dst2[c * PK8 + k8] = ((const s8v*)(WcT + (size_t)(bcol0 + c) * KK))[k8];
        }
    }

    const float bgr  = bg[bcol0 + l15];
    const float bgu  = bg[HH + bcol0 + l15];
    const float bcv  = bc[bcol0 + l15];
    const int   ccol = bcol0 + l15;

    const s8v* sWg8 = (const s8v*)sWg;
    const s8v* sWc8 = (const s8v*)sWc;
    const s8v* bwr = sWg8 + l15 * PK8 + lq;          // r-col weights
    const s8v* bwu = sWg8 + (16 + l15) * PK8 + lq;   // u-col weights
    const s8v* bwc = sWc8 + l15 * PK8 + lq;          // cand weights
    const s8v* bwrx = bwr + 16 * ks;                 // x chunks [4ks..4ks+4)
    const s8v* bwux = bwu + 16 * ks;
    const s8v* bwrh = bwr + 64 + 32 * ks;            // h chunks [8ks..8ks+8)
    const s8v* bwuh = bwu + 64 + 32 * ks;
    const s8v* bwcx = bwc + 16 * ks;
    const s8v* bwch = bwc + 64 + 32 * ks;

    float hprev[4] = {0.f, 0.f, 0.f, 0.f};   // valid in ks==0 waves
    float ureg[4]  = {0.f, 0.f, 0.f, 0.f};

    __syncthreads();

#pragma unroll 1
    for (int t = 0; t < TT; ++t) {
        const s8v* xk = (const s8v*)(Xbf + (size_t)arow * (TT * DD) + (size_t)t * DD) + lq + 16 * ks;
        s8v x0 = xk[0], x1 = xk[4], x2 = xk[8], x3 = xk[12];   // shared by A & B

        // ========== Phase A: gates. poll -> issue loads -> x-MFMAs in shadow ==========
        f4v ar0 = {0,0,0,0}, ar1 = {0,0,0,0}, au0 = {0,0,0,0}, au1 = {0,0,0,0};
        if (t > 0) {
            poll16(gflagB, ks * 16, rt, t, lane);    // h_{t-1} from my 16 producers
            const unsigned short* hp = hpub + (DEEP ? (size_t)(t - 1) * BBHH : 0)
                                     + (size_t)arow * HH + ks * 256 + lq * 8;
            u4v hb[8];
            if (DEEP) {
#pragma unroll
                for (int j = 0; j < 8; ++j) hb[j] = *reinterpret_cast<const u4v*>(hp + (size_t)j * 32);
                ar0 = MFMA(x0, bwrx[0],  ar0); au0 = MFMA(x0, bwux[0],  au0);
                ar1 = MFMA(x1, bwrx[4],  ar1); au1 = MFMA(x1, bwux[4],  au1);
                ar0 = MFMA(x2, bwrx[8],  ar0); au0 = MFMA(x2, bwux[8],  au0);
                ar1 = MFMA(x3, bwrx[12], ar1); au1 = MFMA(x3, bwux[12], au1);
            } else {
#pragma unroll
                for (int j = 0; j < 8; ++j) hb[j] = cload16(hp + (size_t)j * 32);
                ar0 = MFMA(x0, bwrx[0],  ar0); au0 = MFMA(x0, bwux[0],  au0);
                ar1 = MFMA(x1, bwrx[4],  ar1); au1 = MFMA(x1, bwux[4],  au1);
                ar0 = MFMA(x2, bwrx[8],  ar0); au0 = MFMA(x2, bwux[8],  au0);
                ar1 = MFMA(x3, bwrx[12], ar1); au1 = MFMA(x3, bwux[12], au1);
                WAIT_VM(0);
            }
            ar0 = MFMA(B16(hb[0]), bwrh[0],  ar0); au0 = MFMA(B16(hb[0]), bwuh[0],  au0);
            ar1 = MFMA(B16(hb[1]), bwrh[4],  ar1); au1 = MFMA(B16(hb[1]), bwuh[4],  au1);
            ar0 = MFMA(B16(hb[2]), bwrh[8],  ar0); au0 = MFMA(B16(hb[2]), bwuh[8],  au0);
            ar1 = MFMA(B16(hb[3]), bwrh[12], ar1); au1 = MFMA(B16(hb[3]), bwuh[12], au1);
            ar0 = MFMA(B16(hb[4]), bwrh[16], ar0); au0 = MFMA(B16(hb[4]), bwuh[16], au0);
            ar1 = MFMA(B16(hb[5]), bwrh[20], ar1); au1 = MFMA(B16(hb[5]), bwuh[20], au1);
            ar0 = MFMA(B16(hb[6]), bwrh[24], ar0); au0 = MFMA(B16(hb[6]), bwuh[24], au0);
            ar1 = MFMA(B16(hb[7]), bwrh[28], ar1); au1 = MFMA(B16(hb[7]), bwuh[28], au1);
        } else {
            ar0 = MFMA(x0, bwrx[0],  ar0); au0 = MFMA(x0, bwux[0],  au0);
            ar1 = MFMA(x1, bwrx[4],  ar1); au1 = MFMA(x1, bwux[4],  au1);
            ar0 = MFMA(x2, bwrx[8],  ar0); au0 = MFMA(x2, bwux[8],  au0);
            ar1 = MFMA(x3, bwrx[12], ar1); au1 = MFMA(x3, bwux[12], au1);
        }

        // ---- cross-wave K-reduction ----
        f4v pr = ar0 + ar1, pu = au0 + au1;
        if (ks > 0) {
#pragma unroll
            for (int i = 0; i < 4; ++i) {
                sP[ks - 1][rt][0][lq * 4 + i][l15] = pr[i];
                sP[ks - 1][rt][1][lq * 4 + i][l15] = pu[i];
            }
        }
        __syncthreads();                             // S1: A partials ready
        float zr[4], zu[4];
        if (ks == 0) {
#pragma unroll
            for (int i = 0; i < 4; ++i) {
                int rr = lq * 4 + i;
                zr[i] = pr[i] + sP[0][rt][0][rr][l15] + sP[1][rt][0][rr][l15]
                              + sP[2][rt][0][rr][l15] + bgr;
                zu[i] = pu[i] + sP[0][rt][1][rr][l15] + sP[1][rt][1][rr][l15]
                              + sP[2][rt][1][rr][l15] + bgu;
            }
        }
        __syncthreads();                             // S2: sP free for phase B
        if (ks == 0) {
#pragma unroll
            for (int i = 0; i < 4; ++i) {
                float r = 1.f / (1.f + __expf(-zr[i]));
                ureg[i] = 1.f / (1.f + __expf(-zu[i]));
                __hip_bfloat16 hb16 = __float2bfloat16(r * hprev[i]);
                sStage[rt][lq * 4 + i][l15] = *(unsigned short*)&hb16;
            }
            if (t > 0) {                             // rh_0 == 0, never read
                int prow = lane >> 2, pc4 = (lane & 3) * 4;
                u2v v = *reinterpret_cast<const u2v*>(&sStage[rt][prow][pc4]);  // same-wave LDS
                cstore8(rpub + (DEEP ? (size_t)t * BBHH : 0)
                             + (size_t)(roff + prow) * HH + bcol0 + pc4, v);
                asm volatile("s_waitcnt vmcnt(0)" ::: "memory");
                if (lane == 0)
                    __hip_atomic_store(&gflagA[(b * 2 + rt) * 16], t,
                                       __ATOMIC_RELAXED, __HIP_MEMORY_SCOPE_AGENT);
            }
        }

        // ========== Phase B: candidate. poll -> loads -> x-MFMAs in shadow ==========
        f4v c0 = {0,0,0,0}, c1 = {0,0,0,0};
        if (t > 0) {
            poll16(gflagA, ks * 16, rt, t, lane);    // rh_t from my 16 producers
            const unsigned short* rp = rpub + (DEEP ? (size_t)t * BBHH : 0)
                                     + (size_t)arow * HH + ks * 256 + lq * 8;
            u4v rb[8];
            if (DEEP) {
#pragma unroll
                for (int j = 0; j < 8; ++j) rb[j] = *reinterpret_cast<const u4v*>(rp + (size_t)j * 32);
                c0 = MFMA(x0, bwcx[0],  c0); c1 = MFMA(x1, bwcx[4],  c1);
                c0 = MFMA(x2, bwcx[8],  c0); c1 = MFMA(x3, bwcx[12], c1);
            } else {
#pragma unroll
                for (int j = 0; j < 8; ++j) rb[j] = cload16(rp + (size_t)j * 32);
                c0 = MFMA(x0, bwcx[0],  c0); c1 = MFMA(x1, bwcx[4],  c1);
                c0 = MFMA(x2, bwcx[8],  c0); c1 = MFMA(x3, bwcx[12], c1);
                WAIT_VM(0);
            }
            c0 = MFMA(B16(rb[0]), bwch[0],  c0); c1 = MFMA(B16(rb[1]), bwch[4],  c1);
            c0 = MFMA(B16(rb[2]), bwch[8],  c0); c1 = MFMA(B16(rb[3]), bwch[12], c1);
            c0 = MFMA(B16(rb[4]), bwch[16], c0); c1 = MFMA(B16(rb[5]), bwch[20], c1);
            c0 = MFMA(B16(rb[6]), bwch[24], c0); c1 = MFMA(B16(rb[7]), bwch[28], c1);
        } else {
            c0 = MFMA(x0, bwcx[0],  c0); c1 = MFMA(x1, bwcx[4],  c1);
            c0 = MFMA(x2, bwcx[8],  c0); c1 = MFMA(x3, bwcx[12], c1);
        }

        f4v pc = c0 + c1;
        if (ks > 0) {
#pragma unroll
            for (int i = 0; i < 4; ++i) sP[ks - 1][rt][0][lq * 4 + i][l15] = pc[i];
        }
        __syncthreads();                             // S3: B partials ready
        float zc[4];
        if (ks == 0) {
#pragma unroll
            for (int i = 0; i < 4; ++i) {
                int rr = lq * 4 + i;
                zc[i] = pc[i] + sP[0][rt][0][rr][l15] + sP[1][rt][0][rr][l15]
                              + sP[2][rt][0][rr][l15] + bcv;
            }
        }
        __syncthreads();                             // S4: sP free for next step
        if (ks == 0) {
#pragma unroll
            for (int i = 0; i < 4; ++i) {
                float e = __expf(2.f * zc[i]);
                float cv = 1.f - 2.f / (e + 1.f);
                float hn = ureg[i] * hprev[i] + (1.f - ureg[i]) * cv;
                hprev[i] = hn;
                __hip_bfloat16 hb16 = __float2bfloat16(hn);
                sStage[rt][lq * 4 + i][l15] = *(unsigned short*)&hb16;
            }
            int prow = lane >> 2, pc4 = (lane & 3) * 4;
            u2v v = *reinterpret_cast<const u2v*>(&sStage[rt][prow][pc4]);      // same-wave LDS
            cstore8(hpub + (DEEP ? (size_t)t * BBHH : 0)
                         + (size_t)(roff + prow) * HH + bcol0 + pc4, v);
            asm volatile("s_waitcnt vmcnt(0)" ::: "memory");
            if (lane == 0)
                __hip_atomic_store(&gflagB[(b * 2 + rt) * 16], t + 1,
                                   __ATOMIC_RELAXED, __HIP_MEMORY_SCOPE_AGENT);
            // out stores AFTER the flag — off the rendezvous critical path
#pragma unroll
            for (int i = 0; i < 4; ++i) {
                int row = roff + lq * 4 + i;
                out[(size_t)row * (TT * HH) + (size_t)t * HH + ccol] = hprev[i];
            }
        }
    }
}

// ---------------------------------------------------------------------------
extern "C" void kernel_launch(void* const* d_in, const int* in_sizes, int n_in,
                              void* d_out, int out_size, void* d_ws, size_t ws_size,
                              hipStream_t stream) {
    const float* X  = (const float*)d_in[0];
    const float* gk = (const float*)d_in[1];
    const float* gb = (const float*)d_in[2];
    const float* ck = (const float*)d_in[3];
    const float* cb = (const float*)d_in[4];
    float* out = (float*)d_out;
    char* ws = (char*)d_ws;
    if (ws_size < NEED_S) return;

    const bool deep = (ws_size >= NEED_D);

    unsigned short* WgT  = (unsigned short*)(ws + OFF_WGT);
    unsigned short* WcT  = (unsigned short*)(ws + OFF_WCT);
    unsigned short* Xbf  = (unsigned short*)(ws + OFF_XBF);
    unsigned short* hpub = (unsigned short*)(ws + OFF_HPB);
    unsigned short* rpub = (unsigned short*)(ws + (deep ? OFF_RPB_D : OFF_RPB_S));
    int*            gflagA = (int*)(ws + (deep ? OFF_FLG_D : OFF_FLG_S));
    int*            gflagB = gflagA + NBLK * 2 * 16;

    hipMemsetAsync(gflagA, 0, SZ_FLG, stream);

    dim3 tb(256);
    wtr_kernel<<<dim3(2 * HH / 32, KK / 32), tb, 0, stream>>>(gk, WgT, 2 * HH);
    wtr_kernel<<<dim3(HH / 32, KK / 32), tb, 0, stream>>>(ck, WcT, HH);
    xconv_kernel<<<(BB * TT * DD) / (256 * 4), tb, 0, stream>>>(X, Xbf);

    if (deep)
        gru_kernel<true><<<NBLK, dim3(TPB), 0, stream>>>(Xbf, WgT, WcT, gb, cb, out,
                                                         hpub, rpub, gflagA, gflagB);
    else
        gru_kernel<false><<<NBLK, dim3(TPB), 0, stream>>>(Xbf, WgT, WcT, gb, cb, out,
                                                          hpub, rpub, gflagA, gflagB);
}